// Round 1
// baseline (113.952 us; speedup 1.0000x reference)
//
#include <hip/hip_runtime.h>

// DeepFilter: P_r = xr*fr - xi*fi, P_i = 2*xr*fi (elementwise), out = 3x5
// zero-padded box sum of P over (freq d, time t). Memory-bound:
// 64 MiB in + 32 MiB out => ~16 us floor at 6.3 TB/s.
//
// R7: pipelined multi-tile blocks (T14 async-STAGE split).
// Theory: R6's per-block [load -> vmcnt(0) -> LDS -> barrier -> compute]
// serialization exposes full HBM latency per tile and idles VMEM ~20% of
// each block's lifetime (convoying across homogeneous blocks). Kernel ran
// ~26.5 us vs ~18.5 us copy-equivalent floor (~70% of the BW the harness
// fills achieve). Fix: each block owns 4 consecutive time tiles with
// double-buffered LDS; per tile: issue NEXT tile's global loads ->
// compute+store CURRENT tile from LDS (covers load latency) ->
// P-multiply + LDS-write of next tile (sole vmcnt wait) -> one barrier.
// Grid 1024 blocks = 4/CU, 16 waves/CU; __launch_bounds__(256,4) caps
// VGPR at 128 (staging adds 8 float4 = 32 VGPR).
// Prediction: kernel ~26.5 -> ~20-22 us, bench 113 -> ~106-108 us.

#define BB 8
#define DD 256
#define TT_FULL 2048
#define DTILE 8
#define TTILE 128
#define CHUNKS 4               // time tiles per block, pipelined
#define RROWS (DTILE + 2)      // 10
#define RCOLS4 34              // float4s per halo row (cols t0-4 .. t0+131)
#define LSTRIDE 136            // floats per LDS row (16B-aligned)
#define NSLOTS (RROWS * RCOLS4)  // 340 load work-items per tile

__global__ __launch_bounds__(256, 4) void deepfilter_kernel(
    const float* __restrict__ xr, const float* __restrict__ xi,
    const float* __restrict__ fr, const float* __restrict__ fi,
    float* __restrict__ out)
{
    __shared__ float Pr[2][RROWS][LSTRIDE];   // 2 x 5.44 KB
    __shared__ float Pi[2][RROWS][LSTRIDE];   // total LDS 21.76 KB

    const int tg0 = blockIdx.x * (TTILE * CHUNKS);  // 0,512,1024,1536
    const int dt  = blockIdx.y;        // 0..31  freq tile
    const int b   = blockIdx.z;        // 0..7   batch
    const int d0  = dt * DTILE;
    const int tid = threadIdx.x;

    const size_t base_in = (size_t)b * DD * TT_FULL;

    // ---- per-slot geometry (slot s covers work-item tid + s*256; 340 total)
    const int nslot = (tid < NSLOTS - 256) ? 2 : 1;   // tid<84 -> 2 slots
    int srow[2], sc4[2];
    bool sok[2];
    size_t sroff[2];
    #pragma unroll
    for (int s = 0; s < 2; ++s) {
        const int idx = tid + s * 256;
        srow[s] = idx / RCOLS4;
        sc4[s]  = idx - srow[s] * RCOLS4;
        const int d = d0 + srow[s] - 1;
        sok[s] = ((unsigned)d < (unsigned)DD) && (idx < NSLOTS);
        sroff[s] = base_in + (size_t)d * TT_FULL;
    }

    // staged raw inputs for the in-flight tile (8 float4 = 32 VGPR)
    float4 sR[2], sI[2], sG[2], sH[2];

    // issue global loads for tile starting at t0 into registers
    auto LOAD = [&](int t0) {
        #pragma unroll
        for (int s = 0; s < 2; ++s) {
            if (s && nslot < 2) break;
            float4 r4 = {0,0,0,0}, i4 = {0,0,0,0};
            float4 g4 = {0,0,0,0}, h4 = {0,0,0,0};
            if (sok[s]) {
                const int tg = t0 - 4 + (sc4[s] << 2);
                const size_t roff = sroff[s];
                if (tg >= 0 && tg <= TT_FULL - 4) {
                    r4 = *(const float4*)(xr + roff + tg);
                    i4 = *(const float4*)(xi + roff + tg);
                    g4 = *(const float4*)(fr + roff + tg);
                    h4 = *(const float4*)(fi + roff + tg);
                } else {
                    float rr[4], ii[4], gg[4], hh[4];
                    #pragma unroll
                    for (int j = 0; j < 4; ++j) {
                        const int t = tg + j;
                        const bool okt = (unsigned)t < (unsigned)TT_FULL;
                        rr[j] = okt ? xr[roff + t] : 0.f;
                        ii[j] = okt ? xi[roff + t] : 0.f;
                        gg[j] = okt ? fr[roff + t] : 0.f;
                        hh[j] = okt ? fi[roff + t] : 0.f;
                    }
                    r4 = make_float4(rr[0], rr[1], rr[2], rr[3]);
                    i4 = make_float4(ii[0], ii[1], ii[2], ii[3]);
                    g4 = make_float4(gg[0], gg[1], gg[2], gg[3]);
                    h4 = make_float4(hh[0], hh[1], hh[2], hh[3]);
                }
            }
            sR[s] = r4; sI[s] = i4; sG[s] = g4; sH[s] = h4;
        }
    };

    // P-multiply staged regs and write to LDS buffer `buf`
    // (compiler places the vmcnt wait here, after COMPUTE has run)
    auto STORE_LDS = [&](int buf) {
        #pragma unroll
        for (int s = 0; s < 2; ++s) {
            if (s && nslot < 2) break;
            const float4 r4 = sR[s], i4 = sI[s], g4 = sG[s], h4 = sH[s];
            float4 pr4, pi4;
            pr4.x = r4.x * g4.x - i4.x * h4.x;
            pr4.y = r4.y * g4.y - i4.y * h4.y;
            pr4.z = r4.z * g4.z - i4.z * h4.z;
            pr4.w = r4.w * g4.w - i4.w * h4.w;
            pi4.x = 2.f * r4.x * h4.x;
            pi4.y = 2.f * r4.y * h4.y;
            pi4.z = 2.f * r4.z * h4.z;
            pi4.w = 2.f * r4.w * h4.w;
            *(float4*)&Pr[buf][srow[s]][sc4[s] << 2] = pr4;
            *(float4*)&Pi[buf][srow[s]][sc4[s] << 2] = pi4;
        }
    };

    // ---- phase-2 geometry: thread -> 4 consecutive output cols of one row.
    // LDS col l holds global t = t0 - 4 + l; output col c uses window
    // l = c+2 .. c+6.
    const int orow = tid >> 5;           // 0..7
    const int oc   = (tid & 31) << 2;    // 0,4,..,124 (16B-aligned)

    auto COMPUTE = [&](int buf, int t0) {
        float4 Ar = {0,0,0,0}, Br = {0,0,0,0};
        float2 Cr = {0,0};
        float4 Ai = {0,0,0,0}, Bi = {0,0,0,0};
        float2 Ci = {0,0};
        #pragma unroll
        for (int kf = 0; kf < 3; ++kf) {
            const float* rp = &Pr[buf][orow + kf][oc];
            const float* ip = &Pi[buf][orow + kf][oc];
            float4 v0 = *(const float4*)rp;          // cols oc   .. oc+3
            float4 v1 = *(const float4*)(rp + 4);    // cols oc+4 .. oc+7
            float2 v2 = *(const float2*)(rp + 8);    // cols oc+8 .. oc+9
            Ar.x += v0.x; Ar.y += v0.y; Ar.z += v0.z; Ar.w += v0.w;
            Br.x += v1.x; Br.y += v1.y; Br.z += v1.z; Br.w += v1.w;
            Cr.x += v2.x; Cr.y += v2.y;
            float4 w0 = *(const float4*)ip;
            float4 w1 = *(const float4*)(ip + 4);
            float2 w2 = *(const float2*)(ip + 8);
            Ai.x += w0.x; Ai.y += w0.y; Ai.z += w0.z; Ai.w += w0.w;
            Bi.x += w1.x; Bi.y += w1.y; Bi.z += w1.z; Bi.w += w1.w;
            Ci.x += w2.x; Ci.y += w2.y;
        }

        // s[i] = 3-row column sum at LDS col oc+2+i ; out[j] = sum s[j..j+4]
        float4 outr, outi;
        {
            const float s0 = Ar.z, s1 = Ar.w, s2 = Br.x, s3 = Br.y,
                        s4 = Br.z, s5 = Br.w, s6 = Cr.x, s7 = Cr.y;
            const float m = s3 + s4;
            const float a = s1 + s2 + m;
            const float bmid = s2 + m + s5;
            outr.x = s0 + a;
            outr.y = a + s5;
            outr.z = bmid + s6;
            outr.w = m + s5 + s6 + s7;
        }
        {
            const float s0 = Ai.z, s1 = Ai.w, s2 = Bi.x, s3 = Bi.y,
                        s4 = Bi.z, s5 = Bi.w, s6 = Ci.x, s7 = Ci.y;
            const float m = s3 + s4;
            const float a = s1 + s2 + m;
            const float bmid = s2 + m + s5;
            outi.x = s0 + a;
            outi.y = a + s5;
            outi.z = bmid + s6;
            outi.w = m + s5 + s6 + s7;
        }

        const size_t obase = (size_t)b * (2 * DD * TT_FULL)
                           + (size_t)(d0 + orow) * TT_FULL + (t0 + oc);
        *(float4*)&out[obase] = outr;                              // real half
        *(float4*)&out[obase + (size_t)DD * TT_FULL] = outi;       // imag half
    };

    // ---- pipeline: prologue tile 0, then for each tile k:
    //   issue loads(k+1) | compute+store(k) | P-mul + LDS-write(k+1) | barrier
    // One barrier per tile (same as R6), but global loads for k+1 stay in
    // flight across compute of k instead of stalling at a vmcnt(0) drain.
    LOAD(tg0);
    STORE_LDS(0);
    __syncthreads();

    #pragma unroll
    for (int k = 0; k < CHUNKS; ++k) {
        if (k + 1 < CHUNKS) LOAD(tg0 + (k + 1) * TTILE);
        COMPUTE(k & 1, tg0 + k * TTILE);
        if (k + 1 < CHUNKS) {
            STORE_LDS((k + 1) & 1);   // buf (k+1)&1 last read in iter k-1,
                                      // protected by that iter's barrier
            __syncthreads();
        }
    }
}

extern "C" void kernel_launch(void* const* d_in, const int* in_sizes, int n_in,
                              void* d_out, int out_size, void* d_ws, size_t ws_size,
                              hipStream_t stream) {
    const float* xr = (const float*)d_in[0];
    const float* xi = (const float*)d_in[1];
    const float* fr = (const float*)d_in[2];
    const float* fi = (const float*)d_in[3];
    float* out = (float*)d_out;

    dim3 grid(TT_FULL / (TTILE * CHUNKS), DD / DTILE, BB);  // (4, 32, 8) = 1024
    deepfilter_kernel<<<grid, 256, 0, stream>>>(xr, xi, fr, fi, out);
}